// Round 7
// baseline (336.202 us; speedup 1.0000x reference)
//
#include <hip/hip_runtime.h>
#include <cmath>

// PhaseAwareClassifier on MI355X — R24: 2-bank kt pipeline + 4 img/block +
// shuffle energy (zero barriers after staging).
// R23 post-mortem: col-owner @2/SIMD = 225.9us, VGPR 92/256 — step 17k cyc
// vs ~7k LDS+MFMA floor -> ~9k exposed ds_read latency from the serial
// load->wait->MFMA kt body (both waves in identical phase). Fixes:
//  1) 2-bank register pipeline over kt: LOAD(k0) LOAD(k1) MFMA(k0) LOAD(k2)
//     MFMA(k1) LOAD(k3) MFMA(k2) LOAD(k4) MFMA(k3) MFMA(k4). Spends ~160
//     VGPR of headroom; per-acc MFMA order still kt-ascending -> bit-exact.
//  2) grid 256, 4 images per block: conn staged once/CU, one residency
//     round, no inter-round tails.
//  3) energy via quad shfl_xor reduce + atomicAdd (kills scrE alias, the
//     serial 128-iter sum, and ALL post-staging barriers -> waves fully
//     independent; phases drift -> LDS unit naturally interleaved).
// Discipline: unroll(1) on t/img loops, static bank/acc indices (rule #20),
// flat __launch_bounds__(512) only (R19/R20 lesson).
// LDS: conn 82,944 + OBP 73,728 + gsp 576 = 157,248 B -> 1 block/CU.

#define NSTEPS  10
#define INJ_ST  4
#define MT      144          // padded M (9 tiles of 16)

typedef __bf16 bf16x8 __attribute__((ext_vector_type(8)));
typedef __bf16 bf16x4 __attribute__((ext_vector_type(4)));
typedef short  short8 __attribute__((ext_vector_type(8)));
typedef float  f32x4  __attribute__((ext_vector_type(4)));

// workspace layout (float offsets)
#define WS_MAX    0          // 1      enc_max (uint-ordered float)
#define WS_ENERGY 64         // 1280   energy[b][10]
#define WS_GSP    2048       // 144    g2q[j] = -0.5*log2(e)*softplus(gain)
#define WS_CONN   4096       // 2 bf16 mats [20][144][8] chunked: Cr, Ci

// fused prep: blocks 0..97 = image absmax; blocks 98.. = conn + gsp tables
__global__ void k_pre(const float* __restrict__ img,
                      const float* __restrict__ cr, const float* __restrict__ ci,
                      const float* __restrict__ phase, const float* __restrict__ gain,
                      float* ws) {
    if (blockIdx.x < 98) {
        __shared__ float sm[256];
        float v = 0.f;
        for (int i = blockIdx.x * 256 + threadIdx.x; i < 128 * 28 * 28; i += 98 * 256)
            v = fmaxf(v, fabsf(img[i]));
        sm[threadIdx.x] = v;
        __syncthreads();
        for (int s = 128; s > 0; s >>= 1) {
            if (threadIdx.x < s) sm[threadIdx.x] = fmaxf(sm[threadIdx.x], sm[threadIdx.x + s]);
            __syncthreads();
        }
        if (threadIdx.x == 0)
            atomicMax((unsigned int*)(ws + WS_MAX), __float_as_uint(sm[0]));
        return;
    }
    int i = (blockIdx.x - 98) * 256 + threadIdx.x;
    __bf16* Cb = (__bf16*)(ws + WS_CONN);
    const int NCE = MT * 160;              // 23040 (m,k) pairs
    if (i < NCE) {
        int m = i / 160, k = i % 160;
        float vr = 0.f, vi = 0.f;
        if (m < 131 && k < 131) {
            float a = cr[k * 131 + m], b = ci[k * 131 + m];
            float ph = phase[m];
            float cp = cosf(ph), sp = sinf(ph);
            vr = a * cp - b * sp;
            vi = a * sp + b * cp;
        }
        int ca = ((k >> 3) * MT + m) * 8 + (k & 7);    // chunked addr
        Cb[ca]       = (__bf16)vr;
        Cb[NCE + ca] = (__bf16)vi;
    } else if (i < NCE + MT) {
        int j = i - NCE;
        float g = 0.f;
        if (j < 131) {
            float x = gain[j];
            g = (x > 20.f) ? x : log1pf(expf(x));  // softplus
        }
        ws[WS_GSP + j] = g * -0.72134754543f;       // -2*log2(e)*g / 4
    }
}

static __device__ __forceinline__ f32x4 MF(bf16x8 a, bf16x8 b, f32x4 c) {
    return __builtin_amdgcn_mfma_f32_16x16x32_bf16(a, b, c, 0, 0, 0);
}
static __device__ __forceinline__ bf16x8 bneg(bf16x8 a) {
    short8 t = __builtin_bit_cast(short8, a) ^ (short8)(short)0x8000;
    return __builtin_bit_cast(bf16x8, t);
}

// one complex 16x16 tile accumulation; order identical to R17..R23.
#define CPAIR(AR, AI, BR, BI, BNI, P)                                  \
    accr[P] = MF(AR, BR,  accr[P]);                                    \
    accr[P] = MF(AI, BNI, accr[P]);                                    \
    acci[P] = MF(AR, BI,  acci[P]);                                    \
    acci[P] = MF(AI, BR,  acci[P]);

// load one kt's operands into a register bank (20 ds_reads, burst-issued)
#define LOADK(RK, AR, AI, BR, BI) do {                                 \
    const int rk_ = (RK);                                              \
    const int bb_ = (rk_ * 16 + ln15) * 8;                             \
    BR = *(const bf16x8*)(OWr + bb_);                                  \
    BI = *(const bf16x8*)(OWi + bb_);                                  \
    const int ab_ = (rk_ * MT + ln15) * 8;                             \
    _Pragma("unroll")                                                  \
    for (int mt_ = 0; mt_ < 9; ++mt_) {                                \
        AR[mt_] = *(const bf16x8*)(CrL + ab_ + mt_ * 128);             \
        AI[mt_] = *(const bf16x8*)(CiL + ab_ + mt_ * 128);             \
    }                                                                  \
} while (0)

// consume one bank: 36 MFMAs (9 independent 4-chains)
#define MFMAK(AR, AI, BR, BI) do {                                     \
    bf16x8 bn_ = bneg(BI);                                             \
    _Pragma("unroll")                                                  \
    for (int mt_ = 0; mt_ < 9; ++mt_) {                                \
        CPAIR(AR[mt_], AI[mt_], BR, BI, bn_, mt_)                      \
    }                                                                  \
} while (0)

__global__ __launch_bounds__(512)
void k_main(const float* __restrict__ img, const float* __restrict__ ws,
            float* __restrict__ energy) {
    __shared__ __bf16 CrL[18 * MT * 8];            // 41,472 B
    __shared__ __bf16 CiL[18 * MT * 8];            // 41,472 B
    __shared__ __bf16 OBP[2][8][18 * 16 * 8];      // 73,728 B  [r/i][wave][...]
    __shared__ float  gspL[144];                   // 576 B
    // total 157,248 B -> 1 block/CU, 8 waves = 2/SIMD, col-owner layout.

    const int tid  = threadIdx.x;
    const int lane = tid & 63;
    const int ln15 = lane & 15;
    const int quad = lane >> 4;
    const int w    = __builtin_amdgcn_readfirstlane(tid >> 6);  // 0..7
    const int bs   = blockIdx.x & 7;                // col-slice of each image

    __bf16* __restrict__ OWr = &OBP[0][w][0];
    __bf16* __restrict__ OWi = &OBP[1][w][0];

    // injection scaling (identical rounding chain to R20..R23)
    const float mx = ws[WS_MAX];
    const float sc = (mx > 1e-8f) ? (1.02f / mx) : 1.02f;   // 0.85*4*0.3

    // wave w owns cols [16w, 16w+16) of its slice: single l-value, m = ln15
    const int   l   = (bs * 8 + w) & 63;
    const float wl  = 1.0f - fabsf((float)l - 32.0f) * (1.0f / 64.0f);

    // stage conn chunks 0..17 + gsp -> LDS (the ONLY barrier in the kernel)
    {
        const int4* srcR = (const int4*)(ws + WS_CONN);
        const int4* srcI = (const int4*)(ws + WS_CONN + (MT * 160 / 2));
        int4* dstR = (int4*)CrL;
        int4* dstI = (int4*)CiL;
        for (int i = tid; i < 2592; i += 512) { dstR[i] = srcR[i]; dstI[i] = srcI[i]; }
        if (tid < 144) gspL[tid] = ws[WS_GSP + tid];
    }
    __syncthreads();                                // conn + gsp staged

    // ---- 4 images sequentially; waves fully independent hereafter ----
#pragma unroll 1
    for (int it = 0; it < 4; ++it) {
        const int im   = (blockIdx.x >> 3) + 32 * it;
        const int imgb = im * 784 + (ln15 >> 2) * 28 + (ln15 & 3);

        f32x4 accr[9], acci[9];                     // p = mt
#pragma unroll
        for (int p = 0; p < 9; ++p) { accr[p] = (f32x4)0.f; acci[p] = (f32x4)0.f; }

        // injection: rows j<49 (tiles 0..3)
        auto inj_add = [&]() {
#pragma unroll
            for (int mt = 0; mt < 4; ++mt) {
#pragma unroll
                for (int r = 0; r < 4; ++r) {
                    int j = mt * 16 + quad * 4 + r;
                    if (j < 49) {
                        int pi = j / 7, pj = j % 7;
                        float px = img[imgb + pi * 112 + pj * 4];
                        float t  = px * sc;
                        accr[mt][r] = fmaf(t, wl, accr[mt][r]);
                    }
                }
            }
        };

        // epilogue: out = a * tanh(g*|f|)/|f| (0.25 folded), write own OB
        auto epilogue = [&]() {
#pragma unroll
            for (int mt = 0; mt < 9; ++mt) {
                f32x4 g2v = *(const f32x4*)(gspL + mt * 16 + quad * 4);
                bf16x4 pr, pi;
#pragma unroll
                for (int r = 0; r < 4; ++r) {
                    float ar = accr[mt][r], ai = acci[mt][r];
                    float mag2 = fmaf(ar, ar, fmaf(ai, ai, 1.6e-7f));
                    float rsq  = __builtin_amdgcn_rsqf(mag2);
                    float e    = __builtin_amdgcn_exp2f(g2v[r] * (mag2 * rsq));
                    float u    = __builtin_amdgcn_rcpf(1.0f + e);
                    float th   = fmaf(-2.0f, e * u, 1.0f);
                    float scv  = th * rsq;
                    pr[r] = (__bf16)(ar * scv); pi[r] = (__bf16)(ai * scv);
                }
                const int off = ((mt * 2 + (quad >> 1)) * 16 + ln15) * 8
                              + (quad & 1) * 4;
                *(bf16x4*)(OWr + off) = pr;
                *(bf16x4*)(OWi + off) = pi;
            }
        };

        inj_add();                                  // t = 0 (out is zero)
        epilogue();                                 // wave-private, no barrier

        // ---- time loop: zero barriers; 2-bank kt software pipeline ----
#pragma unroll 1
        for (int t = 1; t < NSTEPS - 1; ++t) {
#pragma unroll
            for (int p = 0; p < 9; ++p) { accr[p] *= 0.85f; acci[p] *= 0.85f; }
            if (t < INJ_ST) inj_add();

            bf16x8 A0r[9], A0i[9], A1r[9], A1i[9];
            bf16x8 b0r, b0i, b1r, b1i;
            if (t == 1) {
                // out(0) rows >=49 exactly zero -> kt 0,1 only
                LOADK(quad,     A0r, A0i, b0r, b0i);
                LOADK(4 + quad, A1r, A1i, b1r, b1i);
                MFMAK(A0r, A0i, b0r, b0i);          // kt0
                MFMAK(A1r, A1i, b1r, b1i);          // kt1
            } else {
                const int rk4 = (16 + quad > 17) ? 17 : 16 + quad;
                LOADK(quad,      A0r, A0i, b0r, b0i);   // kt0 -> B0
                LOADK(4 + quad,  A1r, A1i, b1r, b1i);   // kt1 -> B1
                MFMAK(A0r, A0i, b0r, b0i);              // kt0
                LOADK(8 + quad,  A0r, A0i, b0r, b0i);   // kt2 -> B0
                MFMAK(A1r, A1i, b1r, b1i);              // kt1
                LOADK(12 + quad, A1r, A1i, b1r, b1i);   // kt3 -> B1
                MFMAK(A0r, A0i, b0r, b0i);              // kt2
                LOADK(rk4,       A0r, A0i, b0r, b0i);   // kt4 -> B0
                MFMAK(A1r, A1i, b1r, b1i);              // kt3
                MFMAK(A0r, A0i, b0r, b0i);              // kt4
            }
            epilogue();                             // wave-private, no barrier
        }

        // ---- t = 9: only rows 121..130 (tiles 7,8) feed energy ----
        accr[7] *= 0.85f; acci[7] *= 0.85f;
        accr[8] *= 0.85f; acci[8] *= 0.85f;
#pragma unroll 1
        for (int kt = 0; kt < 5; ++kt) {
            const int kch = kt * 4 + quad;
            const int rk  = (kch > 17) ? 17 : kch;
            const int bb  = (rk * 16 + ln15) * 8;
            bf16x8 br = *(const bf16x8*)(OWr + bb);
            bf16x8 bi = *(const bf16x8*)(OWi + bb);
            const int ab = (rk * MT + ln15) * 8;
            bf16x8 ar7 = *(const bf16x8*)(CrL + ab + 7 * 128);
            bf16x8 ai7 = *(const bf16x8*)(CiL + ab + 7 * 128);
            bf16x8 ar8 = *(const bf16x8*)(CrL + ab + 8 * 128);
            bf16x8 ai8 = *(const bf16x8*)(CiL + ab + 8 * 128);
            bf16x8 bn = bneg(bi);
            CPAIR(ar7, ai7, br, bi, bn, 7)
            CPAIR(ar8, ai8, br, bi, bn, 8)
        }

        // ---- energy: per-lane |out|^2, quad shfl-reduce over 16 cols,
        // one atomicAdd per (j) from lane ln15==0 of the owning quad ----
#pragma unroll
        for (int mt = 7; mt < 9; ++mt) {
#pragma unroll
            for (int r = 0; r < 4; ++r) {
                int j = mt * 16 + quad * 4 + r;
                if (j >= 121 && j <= 130) {
                    float ar = accr[mt][r], ai = acci[mt][r];
                    float mag2 = fmaf(ar, ar, fmaf(ai, ai, 1.6e-7f));
                    float rsq  = __builtin_amdgcn_rsqf(mag2);
                    float e    = __builtin_amdgcn_exp2f(gspL[j] * (mag2 * rsq));
                    float u    = __builtin_amdgcn_rcpf(1.0f + e);
                    float th   = fmaf(-2.0f, e * u, 1.0f);
                    float scv  = th * rsq;
                    float orv = ar * scv, oiv = ai * scv;
                    float e2 = orv * orv + oiv * oiv;
                    e2 += __shfl_xor(e2, 1);
                    e2 += __shfl_xor(e2, 2);
                    e2 += __shfl_xor(e2, 4);
                    e2 += __shfl_xor(e2, 8);
                    if (ln15 == 0) atomicAdd(energy + im * 10 + (j - 121), e2);
                }
            }
        }
    }
}

__global__ void k_readout(const float* __restrict__ ws,
                          const float* __restrict__ W,
                          const float* __restrict__ bias,
                          float* __restrict__ out) {
    int i = blockIdx.x * 256 + threadIdx.x;
    if (i < 1280) {
        int b = i / 10, o = i % 10;
        float s = bias[o];
#pragma unroll
        for (int f = 0; f < 10; ++f) {
            float feat = log1pf(ws[WS_ENERGY + b * 10 + f] + 1e-8f);
            s = fmaf(feat, W[o * 10 + f], s);
        }
        out[i] = s;
    }
}

extern "C" void kernel_launch(void* const* d_in, const int* in_sizes, int n_in,
                              void* d_out, int out_size, void* d_ws, size_t ws_size,
                              hipStream_t stream) {
    const float* images = (const float*)d_in[0];
    const float* conn_r = (const float*)d_in[1];
    const float* conn_i = (const float*)d_in[2];
    const float* phase  = (const float*)d_in[3];
    const float* gain   = (const float*)d_in[4];
    const float* W      = (const float*)d_in[5];
    const float* bias   = (const float*)d_in[6];
    float* ws  = (float*)d_ws;
    float* out = (float*)d_out;

    // zero WS_MAX + energy (floats 0..1343) — stream-ordered, capture-safe
    hipMemsetAsync(ws, 0, (WS_ENERGY + 1280) * sizeof(float), stream);
    hipLaunchKernelGGL(k_pre, dim3(189), dim3(256), 0, stream,
                       images, conn_r, conn_i, phase, gain, ws);
    hipLaunchKernelGGL(k_main, dim3(256), dim3(512), 0, stream,
                       images, ws, ws + WS_ENERGY);
    hipLaunchKernelGGL(k_readout, dim3(5), dim3(256), 0, stream, ws, W, bias, out);
}

// Round 8
// 268.816 us; speedup vs baseline: 1.2507x; 1.2507x over previous
//
#include <hip/hip_runtime.h>
#include <cmath>

// PhaseAwareClassifier on MI355X — R25: R23 structure + (512,2) bounds +
// 4 img/block + shuffle energy.
// R24 post-mortem: flat __launch_bounds__(512) caps the allocator at 128
// VGPR (it spilled my 2-bank pipeline to 110 MB of in-loop scratch, 299us).
// Allocator rule (R19/R22/R23/R24): VGPR budget = f(min-waves hint), NOT
// live-range demand. R23's 92-VGPR small-window latency exposure and R24's
// spill are the same phenomenon.
// R25: minimal clean test — 8 waves IS 2/SIMD structurally, so declare
// __launch_bounds__(512, 2) -> cap 256. Demand ~180 (acc 72 + burst 72 +
// B 12 + misc). Compiler can now keep the 20-read kt burst live and hoist
// loads over the MFMA block. Keep R24's good parts: grid 256 with 4 images
// per block (conn staged once/CU), quad-shuffle energy + atomicAdd (no
// scrE alias, zero barriers after staging). Math identical -> absmax
// 0.0078125. Discipline: unroll(1) t/img/kt loops, static indices.
// LDS: conn 82,944 + OBP 73,728 + gsp 576 = 157,248 B -> 1 block/CU.

#define NSTEPS  10
#define INJ_ST  4
#define MT      144          // padded M (9 tiles of 16)

typedef __bf16 bf16x8 __attribute__((ext_vector_type(8)));
typedef __bf16 bf16x4 __attribute__((ext_vector_type(4)));
typedef short  short8 __attribute__((ext_vector_type(8)));
typedef float  f32x4  __attribute__((ext_vector_type(4)));

// workspace layout (float offsets)
#define WS_MAX    0          // 1      enc_max (uint-ordered float)
#define WS_ENERGY 64         // 1280   energy[b][10]
#define WS_GSP    2048       // 144    g2q[j] = -0.5*log2(e)*softplus(gain)
#define WS_CONN   4096       // 2 bf16 mats [20][144][8] chunked: Cr, Ci

// fused prep: blocks 0..97 = image absmax; blocks 98.. = conn + gsp tables
__global__ void k_pre(const float* __restrict__ img,
                      const float* __restrict__ cr, const float* __restrict__ ci,
                      const float* __restrict__ phase, const float* __restrict__ gain,
                      float* ws) {
    if (blockIdx.x < 98) {
        __shared__ float sm[256];
        float v = 0.f;
        for (int i = blockIdx.x * 256 + threadIdx.x; i < 128 * 28 * 28; i += 98 * 256)
            v = fmaxf(v, fabsf(img[i]));
        sm[threadIdx.x] = v;
        __syncthreads();
        for (int s = 128; s > 0; s >>= 1) {
            if (threadIdx.x < s) sm[threadIdx.x] = fmaxf(sm[threadIdx.x], sm[threadIdx.x + s]);
            __syncthreads();
        }
        if (threadIdx.x == 0)
            atomicMax((unsigned int*)(ws + WS_MAX), __float_as_uint(sm[0]));
        return;
    }
    int i = (blockIdx.x - 98) * 256 + threadIdx.x;
    __bf16* Cb = (__bf16*)(ws + WS_CONN);
    const int NCE = MT * 160;              // 23040 (m,k) pairs
    if (i < NCE) {
        int m = i / 160, k = i % 160;
        float vr = 0.f, vi = 0.f;
        if (m < 131 && k < 131) {
            float a = cr[k * 131 + m], b = ci[k * 131 + m];
            float ph = phase[m];
            float cp = cosf(ph), sp = sinf(ph);
            vr = a * cp - b * sp;
            vi = a * sp + b * cp;
        }
        int ca = ((k >> 3) * MT + m) * 8 + (k & 7);    // chunked addr
        Cb[ca]       = (__bf16)vr;
        Cb[NCE + ca] = (__bf16)vi;
    } else if (i < NCE + MT) {
        int j = i - NCE;
        float g = 0.f;
        if (j < 131) {
            float x = gain[j];
            g = (x > 20.f) ? x : log1pf(expf(x));  // softplus
        }
        ws[WS_GSP + j] = g * -0.72134754543f;       // -2*log2(e)*g / 4
    }
}

static __device__ __forceinline__ f32x4 MF(bf16x8 a, bf16x8 b, f32x4 c) {
    return __builtin_amdgcn_mfma_f32_16x16x32_bf16(a, b, c, 0, 0, 0);
}
static __device__ __forceinline__ bf16x8 bneg(bf16x8 a) {
    short8 t = __builtin_bit_cast(short8, a) ^ (short8)(short)0x8000;
    return __builtin_bit_cast(bf16x8, t);
}

// one complex 16x16 tile accumulation; order identical to R17..R24.
#define CPAIR(AR, AI, BR, BI, BNI, P)                                  \
    accr[P] = MF(AR, BR,  accr[P]);                                    \
    accr[P] = MF(AI, BNI, accr[P]);                                    \
    acci[P] = MF(AR, BI,  acci[P]);                                    \
    acci[P] = MF(AI, BR,  acci[P]);

__global__ __launch_bounds__(512, 2)
void k_main(const float* __restrict__ img, const float* __restrict__ ws,
            float* __restrict__ energy) {
    __shared__ __bf16 CrL[18 * MT * 8];            // 41,472 B
    __shared__ __bf16 CiL[18 * MT * 8];            // 41,472 B
    __shared__ __bf16 OBP[2][8][18 * 16 * 8];      // 73,728 B  [r/i][wave][...]
    __shared__ float  gspL[144];                   // 576 B
    // total 157,248 B -> 1 block/CU, 8 waves = 2/SIMD (hint matches).

    const int tid  = threadIdx.x;
    const int lane = tid & 63;
    const int ln15 = lane & 15;
    const int quad = lane >> 4;
    const int w    = __builtin_amdgcn_readfirstlane(tid >> 6);  // 0..7
    const int bs   = blockIdx.x & 7;                // col-slice of each image

    __bf16* __restrict__ OWr = &OBP[0][w][0];
    __bf16* __restrict__ OWi = &OBP[1][w][0];

    // injection scaling (identical rounding chain to R20..R24)
    const float mx = ws[WS_MAX];
    const float sc = (mx > 1e-8f) ? (1.02f / mx) : 1.02f;   // 0.85*4*0.3

    // wave w owns cols [16w, 16w+16) of its slice: single l-value, m = ln15
    const int   l   = (bs * 8 + w) & 63;
    const float wl  = 1.0f - fabsf((float)l - 32.0f) * (1.0f / 64.0f);

    // stage conn chunks 0..17 + gsp -> LDS (the ONLY barrier in the kernel)
    {
        const int4* srcR = (const int4*)(ws + WS_CONN);
        const int4* srcI = (const int4*)(ws + WS_CONN + (MT * 160 / 2));
        int4* dstR = (int4*)CrL;
        int4* dstI = (int4*)CiL;
        for (int i = tid; i < 2592; i += 512) { dstR[i] = srcR[i]; dstI[i] = srcI[i]; }
        if (tid < 144) gspL[tid] = ws[WS_GSP + tid];
    }
    __syncthreads();                                // conn + gsp staged

    // ---- 4 images sequentially; waves fully independent hereafter ----
#pragma unroll 1
    for (int it = 0; it < 4; ++it) {
        const int im   = (blockIdx.x >> 3) + 32 * it;
        const int imgb = im * 784 + (ln15 >> 2) * 28 + (ln15 & 3);

        f32x4 accr[9], acci[9];                     // p = mt
#pragma unroll
        for (int p = 0; p < 9; ++p) { accr[p] = (f32x4)0.f; acci[p] = (f32x4)0.f; }

        // injection: rows j<49 (tiles 0..3)
        auto inj_add = [&]() {
#pragma unroll
            for (int mt = 0; mt < 4; ++mt) {
#pragma unroll
                for (int r = 0; r < 4; ++r) {
                    int j = mt * 16 + quad * 4 + r;
                    if (j < 49) {
                        int pi = j / 7, pj = j % 7;
                        float px = img[imgb + pi * 112 + pj * 4];
                        float t  = px * sc;
                        accr[mt][r] = fmaf(t, wl, accr[mt][r]);
                    }
                }
            }
        };

        // epilogue: out = a * tanh(g*|f|)/|f| (0.25 folded), write own OB
        auto epilogue = [&]() {
#pragma unroll
            for (int mt = 0; mt < 9; ++mt) {
                f32x4 g2v = *(const f32x4*)(gspL + mt * 16 + quad * 4);
                bf16x4 pr, pi;
#pragma unroll
                for (int r = 0; r < 4; ++r) {
                    float ar = accr[mt][r], ai = acci[mt][r];
                    float mag2 = fmaf(ar, ar, fmaf(ai, ai, 1.6e-7f));
                    float rsq  = __builtin_amdgcn_rsqf(mag2);
                    float e    = __builtin_amdgcn_exp2f(g2v[r] * (mag2 * rsq));
                    float u    = __builtin_amdgcn_rcpf(1.0f + e);
                    float th   = fmaf(-2.0f, e * u, 1.0f);
                    float scv  = th * rsq;
                    pr[r] = (__bf16)(ar * scv); pi[r] = (__bf16)(ai * scv);
                }
                const int off = ((mt * 2 + (quad >> 1)) * 16 + ln15) * 8
                              + (quad & 1) * 4;
                *(bf16x4*)(OWr + off) = pr;
                *(bf16x4*)(OWi + off) = pi;
            }
        };

        inj_add();                                  // t = 0 (out is zero)
        epilogue();                                 // wave-private, no barrier

        // ---- time loop: zero barriers; burst kt body, 256-VGPR window ----
#pragma unroll 1
        for (int t = 1; t < NSTEPS - 1; ++t) {
#pragma unroll
            for (int p = 0; p < 9; ++p) { accr[p] *= 0.85f; acci[p] *= 0.85f; }
            if (t < INJ_ST) inj_add();

            // t=1: out(0) rows >=49 exactly zero -> kt 0,1 only.
            const int ktEnd = (t == 1) ? 2 : 5;
            // kch 18,19 remap to chunk 17 (zeros both sides). unroll(1): R15.
#pragma unroll 1
            for (int kt = 0; kt < ktEnd; ++kt) {
                const int kch = kt * 4 + quad;
                const int rk  = (kch > 17) ? 17 : kch;
                // ---- load burst: 2 B + 18 A reads, then MFMA block ----
                const int bb  = (rk * 16 + ln15) * 8;
                bf16x8 br = *(const bf16x8*)(OWr + bb);
                bf16x8 bi = *(const bf16x8*)(OWi + bb);
                const int ab = (rk * MT + ln15) * 8;
                bf16x8 ar[9], ai[9];
#pragma unroll
                for (int mt = 0; mt < 9; ++mt) {
                    ar[mt] = *(const bf16x8*)(CrL + ab + mt * 128);
                    ai[mt] = *(const bf16x8*)(CiL + ab + mt * 128);
                }
                bf16x8 bn = bneg(bi);
#pragma unroll
                for (int mt = 0; mt < 9; ++mt) {
                    CPAIR(ar[mt], ai[mt], br, bi, bn, mt)
                }
            }
            epilogue();                             // wave-private, no barrier
        }

        // ---- t = 9: only rows 121..130 (tiles 7,8) feed energy ----
        accr[7] *= 0.85f; acci[7] *= 0.85f;
        accr[8] *= 0.85f; acci[8] *= 0.85f;
#pragma unroll 1
        for (int kt = 0; kt < 5; ++kt) {
            const int kch = kt * 4 + quad;
            const int rk  = (kch > 17) ? 17 : kch;
            const int bb  = (rk * 16 + ln15) * 8;
            bf16x8 br = *(const bf16x8*)(OWr + bb);
            bf16x8 bi = *(const bf16x8*)(OWi + bb);
            const int ab = (rk * MT + ln15) * 8;
            bf16x8 ar7 = *(const bf16x8*)(CrL + ab + 7 * 128);
            bf16x8 ai7 = *(const bf16x8*)(CiL + ab + 7 * 128);
            bf16x8 ar8 = *(const bf16x8*)(CrL + ab + 8 * 128);
            bf16x8 ai8 = *(const bf16x8*)(CiL + ab + 8 * 128);
            bf16x8 bn = bneg(bi);
            CPAIR(ar7, ai7, br, bi, bn, 7)
            CPAIR(ar8, ai8, br, bi, bn, 8)
        }

        // ---- energy: per-lane |out|^2, quad shfl-reduce over 16 cols,
        // one atomicAdd per (j) from lane ln15==0 of the owning quad ----
#pragma unroll
        for (int mt = 7; mt < 9; ++mt) {
#pragma unroll
            for (int r = 0; r < 4; ++r) {
                int j = mt * 16 + quad * 4 + r;
                if (j >= 121 && j <= 130) {
                    float ar = accr[mt][r], ai = acci[mt][r];
                    float mag2 = fmaf(ar, ar, fmaf(ai, ai, 1.6e-7f));
                    float rsq  = __builtin_amdgcn_rsqf(mag2);
                    float e    = __builtin_amdgcn_exp2f(gspL[j] * (mag2 * rsq));
                    float u    = __builtin_amdgcn_rcpf(1.0f + e);
                    float th   = fmaf(-2.0f, e * u, 1.0f);
                    float scv  = th * rsq;
                    float orv = ar * scv, oiv = ai * scv;
                    float e2 = orv * orv + oiv * oiv;
                    e2 += __shfl_xor(e2, 1);
                    e2 += __shfl_xor(e2, 2);
                    e2 += __shfl_xor(e2, 4);
                    e2 += __shfl_xor(e2, 8);
                    if (ln15 == 0) atomicAdd(energy + im * 10 + (j - 121), e2);
                }
            }
        }
    }
}

__global__ void k_readout(const float* __restrict__ ws,
                          const float* __restrict__ W,
                          const float* __restrict__ bias,
                          float* __restrict__ out) {
    int i = blockIdx.x * 256 + threadIdx.x;
    if (i < 1280) {
        int b = i / 10, o = i % 10;
        float s = bias[o];
#pragma unroll
        for (int f = 0; f < 10; ++f) {
            float feat = log1pf(ws[WS_ENERGY + b * 10 + f] + 1e-8f);
            s = fmaf(feat, W[o * 10 + f], s);
        }
        out[i] = s;
    }
}

extern "C" void kernel_launch(void* const* d_in, const int* in_sizes, int n_in,
                              void* d_out, int out_size, void* d_ws, size_t ws_size,
                              hipStream_t stream) {
    const float* images = (const float*)d_in[0];
    const float* conn_r = (const float*)d_in[1];
    const float* conn_i = (const float*)d_in[2];
    const float* phase  = (const float*)d_in[3];
    const float* gain   = (const float*)d_in[4];
    const float* W      = (const float*)d_in[5];
    const float* bias   = (const float*)d_in[6];
    float* ws  = (float*)d_ws;
    float* out = (float*)d_out;

    // zero WS_MAX + energy (floats 0..1343) — stream-ordered, capture-safe
    hipMemsetAsync(ws, 0, (WS_ENERGY + 1280) * sizeof(float), stream);
    hipLaunchKernelGGL(k_pre, dim3(189), dim3(256), 0, stream,
                       images, conn_r, conn_i, phase, gain, ws);
    hipLaunchKernelGGL(k_main, dim3(256), dim3(512), 0, stream,
                       images, ws, ws + WS_ENERGY);
    hipLaunchKernelGGL(k_readout, dim3(5), dim3(256), 0, stream, ws, W, bias, out);
}